// Round 1
// baseline (1008.781 us; speedup 1.0000x reference)
//
#include <hip/hip_runtime.h>

#define DI __device__ __forceinline__

static constexpr int NB   = 50000;   // batch
static constexpr int EPB  = 64;      // elements per 256-thread block (4 lanes/element)
static constexpr int TPB  = 256;
static constexpr int LSTR = 57;      // per-element LDS stride (27 sums + 27 rstd^-1 + pad, odd for banks)
static constexpr int OSUM = 0;
static constexpr int ORSI = 27;

// pair p -> (X,Y), upper-triangle order (0,1),(0,2),...,(7,8)
__constant__ int d_PX[36] = {0,0,0,0,0,0,0,0,1,1,1,1,1,1,1,2,2,2,2,2,2,3,3,3,3,3,4,4,4,4,5,5,5,6,6,7};
__constant__ int d_PY[36] = {1,2,3,4,5,6,7,8,2,3,4,5,6,7,8,3,4,5,6,7,8,4,5,6,7,8,5,6,7,8,6,7,8,7,8,8};

// h[32] += W1fT[col][0..31] * v   (cols padded to 32 floats, j=30,31 are zero)
DI void acc_col(float4 (&h)[8], const float* __restrict__ wt, int col, float v) {
  const float4* wc = reinterpret_cast<const float4*>(wt + (col << 5));
#pragma unroll
  for (int t = 0; t < 8; ++t) {
    float4 w = wc[t];
    h[t].x = fmaf(w.x, v, h[t].x);
    h[t].y = fmaf(w.y, v, h[t].y);
    h[t].z = fmaf(w.z, v, h[t].z);
    h[t].w = fmaf(w.w, v, h[t].w);
  }
}

// Shared feature walker. STATS=true: accumulate raw moments into ws (f64 atomics).
// STATS=false: accumulate h = W1fT * rawfeat, then bias/relu/W2 -> out.
template<bool STATS>
__launch_bounds__(TPB, 3)
__global__ void alpha_main(const float* __restrict__ data,
                           const float* __restrict__ gamma_p,
                           const float* __restrict__ wt,    // W1fT [702][32]
                           const float* __restrict__ b1f,   // [30]
                           const float* __restrict__ W2,    // [30]
                           const float* __restrict__ b2,    // [1]
                           float* __restrict__ out,
                           double* __restrict__ stats)      // [56]
{
  __shared__ float lds[EPB * LSTR];
  const int tid = threadIdx.x;
  const int e = tid >> 2, q = tid & 3;
  const int b = blockIdx.x * EPB + e;
  const float act = (b < NB) ? 1.f : 0.f;
  const int bb = (b < NB) ? b : (NB - 1);
  const float* __restrict__ dptr = data + (size_t)bb * 270;
  float* __restrict__ L = &lds[e * LSTR];

  float4 h[8];
  float zS1[5], zS2[5], zMx[5], zMx2[5], zAv[5], zAv2[5], zMn[5], zMn2[5];
  float cS[16];
  bool neg = false;
  if constexpr (STATS) {
#pragma unroll
    for (int m = 0; m < 5; ++m) {
      zS1[m]=0.f; zS2[m]=0.f; zMx[m]=0.f; zMx2[m]=0.f;
      zAv[m]=0.f; zAv2[m]=0.f; zMn[m]=0.f; zMn2[m]=0.f;
    }
#pragma unroll
    for (int k = 0; k < 16; ++k) cS[k] = 0.f;
  } else {
#pragma unroll
    for (int t = 0; t < 8; ++t) h[t] = make_float4(0.f, 0.f, 0.f, 0.f);
    neg = (gamma_p[0] < 0.f);
  }

  // ---------- phase 1: rows owned by lane q ----------
  for (int r = q; r < 9; r += 4) {
    float z[30];
#pragma unroll
    for (int t = 0; t < 15; ++t) {
      float2 v = *reinterpret_cast<const float2*>(dptr + r * 30 + 2 * t);
      z[2*t] = v.x; z[2*t+1] = v.y;
    }
    float vals[5][3];
#pragma unroll
    for (int s = 0; s < 3; ++s) {
      float sum = 0.f, ssq = 0.f, dec = 0.f;
#pragma unroll
      for (int k = 0; k < 10; ++k) {
        float zz = z[s*10 + k];
        sum += zz;
        ssq = fmaf(zz, zz, ssq);
        dec = fmaf(zz, (float)((double)(k + 1) / 55.0), dec);   // matches (k+1)/55 in fp32
      }
      float mZ = sum * 0.1f;
      float var1 = (ssq - sum * sum * 0.1f) * (1.f / 9.f);      // ddof=1 numerator/9
      var1 = fmaxf(var1, 1e-30f);
      float sZ  = sqrtf(var1);
      float zsc = mZ / sZ;
      float rt  = z[s*10 + 9] / z[s*10] - 1.f;
      vals[0][s] = sZ; vals[1][s] = dec; vals[2][s] = zsc; vals[3][s] = rt; vals[4][s] = mZ;
      L[OSUM + r*3 + s] = sum;
      L[ORSI + r*3 + s] = 1.f / sZ;
    }
#pragma unroll
    for (int m = 0; m < 5; ++m) {
      float v0 = vals[m][0], v1 = vals[m][1], v2 = vals[m][2];
      float mx = fmaxf(fmaxf(v0, v1), v2);
      float mn = fminf(fminf(v0, v1), v2);
      float av = (v0 + v1 + v2) * (1.f / 3.f);
      if constexpr (STATS) {
        zS1[m]  += act * (v0 + v1 + v2);
        zS2[m]  += act * (v0*v0 + v1*v1 + v2*v2);
        zMx[m]  += act * mx;  zMx2[m] += act * mx * mx;
        zAv[m]  += act * av;  zAv2[m] += act * av * av;
        zMn[m]  += act * mn;  zMn2[m] += act * mn * mn;
      } else {
        constexpr int ZB[5] = {432, 486, 540, 594, 648};
        const int cb = ZB[m] + r * 3;
        acc_col(h, wt, cb + 0, v0);
        acc_col(h, wt, cb + 1, v1);
        acc_col(h, wt, cb + 2, v2);
        float qmx = neg ? mn : mx, qmn = neg ? mx : mn;
        acc_col(h, wt, ZB[m] + 27 + r, qmx);
        acc_col(h, wt, ZB[m] + 36 + r, av);
        acc_col(h, wt, ZB[m] + 45 + r, qmn);
      }
    }
  }
  __syncthreads();   // row sums/rstd visible to all 4 lanes of each element

  // ---------- phase 2: pairs owned by lane q (9 each, uniform trip count) ----------
  for (int p = q; p < 36; p += 4) {
    const int X = d_PX[p], Y = d_PY[p];
    float zx[30], zy[30];
#pragma unroll
    for (int t = 0; t < 15; ++t) {
      float2 a = *reinterpret_cast<const float2*>(dptr + X * 30 + 2 * t);
      float2 c = *reinterpret_cast<const float2*>(dptr + Y * 30 + 2 * t);
      zx[2*t] = a.x; zx[2*t+1] = a.y;
      zy[2*t] = c.x; zy[2*t+1] = c.y;
    }
    float cv[3], cr[3];
#pragma unroll
    for (int s = 0; s < 3; ++s) {
      float sxy = 0.f;
#pragma unroll
      for (int k = 0; k < 10; ++k) sxy = fmaf(zx[s*10 + k], zy[s*10 + k], sxy);
      float sX = L[OSUM + X*3 + s], sY = L[OSUM + Y*3 + s];
      float cov = (sxy - sX * sY * 0.1f) * (1.f / 9.f);
      cv[s] = cov;
      cr[s] = cov * L[ORSI + X*3 + s] * L[ORSI + Y*3 + s];
    }
    // cov map (base 0)
    {
      float v0 = cv[0], v1 = cv[1], v2 = cv[2];
      float mx = fmaxf(fmaxf(v0, v1), v2);
      float mn = fminf(fminf(v0, v1), v2);
      float av = (v0 + v1 + v2) * (1.f / 3.f);
      if constexpr (STATS) {
        cS[0] += act * (v0 + v1 + v2);
        cS[1] += act * (v0*v0 + v1*v1 + v2*v2);
        cS[2] += act * mx; cS[3] += act * mx * mx;
        cS[4] += act * av; cS[5] += act * av * av;
        cS[6] += act * mn; cS[7] += act * mn * mn;
      } else {
        acc_col(h, wt, p*3 + 0, v0);
        acc_col(h, wt, p*3 + 1, v1);
        acc_col(h, wt, p*3 + 2, v2);
        float qmx = neg ? mn : mx, qmn = neg ? mx : mn;
        acc_col(h, wt, 108 + p, qmx);
        acc_col(h, wt, 144 + p, av);
        acc_col(h, wt, 180 + p, qmn);
      }
    }
    // corr map (base 216)
    {
      float v0 = cr[0], v1 = cr[1], v2 = cr[2];
      float mx = fmaxf(fmaxf(v0, v1), v2);
      float mn = fminf(fminf(v0, v1), v2);
      float av = (v0 + v1 + v2) * (1.f / 3.f);
      if constexpr (STATS) {
        cS[8]  += act * (v0 + v1 + v2);
        cS[9]  += act * (v0*v0 + v1*v1 + v2*v2);
        cS[10] += act * mx; cS[11] += act * mx * mx;
        cS[12] += act * av; cS[13] += act * av * av;
        cS[14] += act * mn; cS[15] += act * mn * mn;
      } else {
        acc_col(h, wt, 216 + p*3 + 0, v0);
        acc_col(h, wt, 216 + p*3 + 1, v1);
        acc_col(h, wt, 216 + p*3 + 2, v2);
        float qmx = neg ? mn : mx, qmn = neg ? mx : mn;
        acc_col(h, wt, 324 + p, qmx);
        acc_col(h, wt, 360 + p, av);
        acc_col(h, wt, 396 + p, qmn);
      }
    }
  }

  if constexpr (STATS) {
    __shared__ double rb[4][56];
    const int wv = tid >> 6, ln = tid & 63;
    auto red1 = [&](float v, int idx) {
      double d = (double)v;
#pragma unroll
      for (int o = 32; o > 0; o >>= 1) d += __shfl_xor(d, o);
      if (ln == 0) rb[wv][idx] = d;
    };
#pragma unroll
    for (int m = 0; m < 5; ++m) {
      red1(zS1[m], (2+m)*8 + 0); red1(zS2[m],  (2+m)*8 + 1);
      red1(zMx[m], (2+m)*8 + 2); red1(zMx2[m], (2+m)*8 + 3);
      red1(zAv[m], (2+m)*8 + 4); red1(zAv2[m], (2+m)*8 + 5);
      red1(zMn[m], (2+m)*8 + 6); red1(zMn2[m], (2+m)*8 + 7);
    }
#pragma unroll
    for (int k = 0; k < 8; ++k) { red1(cS[k], k); red1(cS[8+k], 8 + k); }
    __syncthreads();
    if (tid < 56) {
      double t = rb[0][tid] + rb[1][tid] + rb[2][tid] + rb[3][tid];
      atomicAdd(&stats[tid], t);
    }
  } else {
    // combine the 4 lanes' partial h (quad-aligned butterfly)
#pragma unroll
    for (int t = 0; t < 8; ++t) {
      h[t].x += __shfl_xor(h[t].x, 1); h[t].y += __shfl_xor(h[t].y, 1);
      h[t].z += __shfl_xor(h[t].z, 1); h[t].w += __shfl_xor(h[t].w, 1);
      h[t].x += __shfl_xor(h[t].x, 2); h[t].y += __shfl_xor(h[t].y, 2);
      h[t].z += __shfl_xor(h[t].z, 2); h[t].w += __shfl_xor(h[t].w, 2);
    }
    if (q == 0 && b < NB) {
      float o = b2[0];
#pragma unroll
      for (int j = 0; j < 30; ++j) {
        const int t = j >> 2, c = j & 3;
        float hv = (c == 0) ? h[t].x : (c == 1) ? h[t].y : (c == 2) ? h[t].z : h[t].w;
        hv += b1f[j];
        o = fmaf(W2[j], fmaxf(hv, 0.f), o);
      }
      out[b] = o;
    }
  }
}

// K2: derive the 28 (A,C) affine pairs from global moments and fold into W1fT / b1f.
__launch_bounds__(256)
__global__ void alpha_fold(const double* __restrict__ stats,
                           const float* __restrict__ gp, const float* __restrict__ bp,
                           const float* __restrict__ W1, const float* __restrict__ b1,
                           float* __restrict__ wt, float* __restrict__ b1f)
{
  __shared__ float A_[28], C_[28], sb[30];
  const int tid = threadIdx.x;
  const float gam = gp[0], bet = bp[0];
  const bool neg = (gam < 0.f);
  if (tid < 28) {
    const int m = tid >> 2, kd = tid & 3;
    const int Rm = (m < 2) ? 36 : 9;
    const double Nc = (double)NB * Rm * 3.0;
    const double Np = (double)NB * Rm;
    double mu0 = stats[m*8 + 0] / Nc;
    double v0  = stats[m*8 + 1] / Nc - mu0 * mu0; if (v0 < 0.0) v0 = 0.0;
    double a0 = (double)gam / sqrt(v0 + 1e-5);
    double c0 = (double)bet - a0 * mu0;
    double Av, Cv;
    if (kd == 0) { Av = a0; Cv = c0; }
    else {
      int k0;
      if (kd == 2) k0 = 4;                 // avg
      else if (kd == 1) k0 = neg ? 6 : 2;  // max slot (swap when gamma<0)
      else k0 = neg ? 2 : 6;               // min slot
      double mp = stats[m*8 + k0] / Np;
      double vp = stats[m*8 + k0 + 1] / Np - mp * mp; if (vp < 0.0) vp = 0.0;
      double my = a0 * mp + c0;
      double vy = a0 * a0 * vp;
      double a1 = (double)gam / sqrt(vy + 1e-5);
      double c1 = (double)bet - a1 * my;
      Av = a1 * a0; Cv = a1 * c0 + c1;
    }
    A_[tid] = (float)Av; C_[tid] = (float)Cv;
  }
  if (tid < 30) sb[tid] = 0.f;
  __syncthreads();
  for (int i = tid; i < 702; i += 256) {
    int m, base;
    if (i < 216)      { m = 0; base = 0; }
    else if (i < 432) { m = 1; base = 216; }
    else { int t = (i - 432) / 54; m = 2 + t; base = 432 + t * 54; }
    const int off = i - base;
    const int Rm = (m < 2) ? 36 : 9;
    const int kd = (off < Rm*3) ? 0 : (off < Rm*4) ? 1 : (off < Rm*5) ? 2 : 3;
    const float Av = A_[m*4 + kd], Cv = C_[m*4 + kd];
    for (int j = 0; j < 30; ++j) {
      float w = W1[j * 702 + i];
      wt[i * 32 + j] = w * Av;
      atomicAdd(&sb[j], w * Cv);
    }
    wt[i * 32 + 30] = 0.f; wt[i * 32 + 31] = 0.f;
  }
  __syncthreads();
  if (tid < 30) b1f[tid] = b1[tid] + sb[tid];
}

extern "C" void kernel_launch(void* const* d_in, const int* in_sizes, int n_in,
                              void* d_out, int out_size, void* d_ws, size_t ws_size,
                              hipStream_t stream) {
  const float* data = (const float*)d_in[0];
  const float* gam  = (const float*)d_in[1];
  const float* bet  = (const float*)d_in[2];
  const float* W1   = (const float*)d_in[3];
  const float* b1   = (const float*)d_in[4];
  const float* W2   = (const float*)d_in[5];
  const float* b2   = (const float*)d_in[6];
  float* out = (float*)d_out;

  double* stats = (double*)d_ws;                       // 56 doubles
  float*  b1f   = (float*)((char*)d_ws + 512);         // 30 floats
  float*  wt    = (float*)((char*)d_ws + 1024);        // 702*32 floats (~88 KB)

  hipMemsetAsync(stats, 0, 56 * sizeof(double), stream);
  const int grid = (NB + EPB - 1) / EPB;               // 782
  alpha_main<true ><<<grid, TPB, 0, stream>>>(data, gam, nullptr, nullptr, nullptr, nullptr, nullptr, stats);
  alpha_fold      <<<1,    256, 0, stream>>>(stats, gam, bet, W1, b1, wt, b1f);
  alpha_main<false><<<grid, TPB, 0, stream>>>(data, gam, wt, b1f, W2, b2, out, nullptr);
}

// Round 11
// 472.968 us; speedup vs baseline: 2.1329x; 2.1329x over previous
//
#include <hip/hip_runtime.h>

static constexpr int NB   = 50000;   // batch
static constexpr int TPB  = 256;
static constexpr int EPB  = 64;      // elements per block, 4 lanes/element (Round-0 structure)
static constexpr int GRID = (NB + EPB - 1) / EPB;   // 782
static constexpr int LSTR = 57;      // rowstats stride: sums[27] rsi[27] pad

// GEMV LDS layout: rowstats [64][57] | wbuf [<=270][36]
static constexpr int RSZ  = EPB * LSTR;   // 3648 floats
static constexpr int WBSZ = 270 * 36;     // 9720 floats (largest chunk)
static constexpr int LTOT = RSZ + WBSZ;   // 13368 floats = 53.5 KB

// pair p -> (X,Y), upper-triangle order (0,1),(0,2),...,(7,8)
__constant__ int d_PX[36] = {0,0,0,0,0,0,0,0,1,1,1,1,1,1,1,2,2,2,2,2,2,3,3,3,3,3,4,4,4,4,5,5,5,6,6,7};
__constant__ int d_PY[36] = {1,2,3,4,5,6,7,8,2,3,4,5,6,7,8,3,4,5,6,7,8,4,5,6,7,8,5,6,7,8,6,7,8,7,8,8};

// ---------------- GEMV: Round-0 passed body; wt (stride-32 in ws) staged to LDS (stride-36) ----------------
__launch_bounds__(TPB, 2)
__global__ void alpha_gemv(const float* __restrict__ data,
                           const float* __restrict__ gamma_p,
                           const float* __restrict__ wt,    // [702][32] folded W1^T (Round-0-proven layout)
                           const float* __restrict__ b1f,   // [30]
                           const float* __restrict__ W2,    // [30]
                           const float* __restrict__ b2,    // [1]
                           float* __restrict__ out)
{
  __shared__ float lds[LTOT];
  float* __restrict__ rs = lds;            // rowstats [64][57]
  float* __restrict__ wb = lds + RSZ;      // wt chunk [<=270][36]

  const int tid = threadIdx.x;
  const int e = tid >> 2, q = tid & 3;
  const int b = blockIdx.x * EPB + e;
  const int bb = (b < NB) ? b : (NB - 1);
  const float* __restrict__ dptr = data + (size_t)bb * 270;
  float* __restrict__ re = rs + e * LSTR;
  const bool neg = (gamma_p[0] < 0.f);

  float4 h[8];
#pragma unroll
  for (int t = 0; t < 8; ++t) h[t] = make_float4(0.f, 0.f, 0.f, 0.f);

  // copy ncols columns (32 floats each) from global stride-32 to LDS stride-36
  auto load_chunk = [&](int col0, int ncols) {
    const float4* __restrict__ src = reinterpret_cast<const float4*>(wt + col0 * 32);
    float4* __restrict__ dst = reinterpret_cast<float4*>(wb);
    const int n = ncols * 8;
    for (int i = tid; i < n; i += TPB) {
      const int c = i >> 3, w = i & 7;
      dst[c * 9 + w] = src[i];     // floats c*36 + 4w; pad floats 32..35 never read
    }
  };

  // h[0..31] += wb[col][0..31] * v
  auto acc = [&](int col, float v) {
    const float4* __restrict__ wc = reinterpret_cast<const float4*>(wb + col * 36);
#pragma unroll
    for (int t = 0; t < 8; ++t) {
      float4 w = wc[t];
      h[t].x = fmaf(w.x, v, h[t].x);
      h[t].y = fmaf(w.y, v, h[t].y);
      h[t].z = fmaf(w.z, v, h[t].z);
      h[t].w = fmaf(w.w, v, h[t].w);
    }
  };

  // ---- chunk 1: z-maps, global cols 432..701 -> local 0..269 ----
  load_chunk(432, 270);
  __syncthreads();

  // phase 1 (Round-0 verbatim math): rows owned by lane q
  for (int r = q; r < 9; r += 4) {
    float z[30];
#pragma unroll
    for (int t = 0; t < 15; ++t) {
      float2 v = *reinterpret_cast<const float2*>(dptr + r * 30 + 2 * t);
      z[2*t] = v.x; z[2*t+1] = v.y;
    }
    float vals[5][3];
#pragma unroll
    for (int s = 0; s < 3; ++s) {
      float sum = 0.f, ssq = 0.f, dec = 0.f;
#pragma unroll
      for (int k = 0; k < 10; ++k) {
        float zz = z[s*10 + k];
        sum += zz;
        ssq = fmaf(zz, zz, ssq);
        dec = fmaf(zz, (float)((double)(k + 1) / 55.0), dec);
      }
      float mZ = sum * 0.1f;
      float var1 = fmaxf((ssq - sum * sum * 0.1f) * (1.f / 9.f), 1e-30f);
      float sZ  = sqrtf(var1);
      float zsc = mZ / sZ;
      float rt  = z[s*10 + 9] / z[s*10] - 1.f;
      vals[0][s] = sZ; vals[1][s] = dec; vals[2][s] = zsc; vals[3][s] = rt; vals[4][s] = mZ;
      re[r*3 + s] = sum;
      re[27 + r*3 + s] = 1.f / sZ;
    }
#pragma unroll
    for (int m = 0; m < 5; ++m) {
      const float v0 = vals[m][0], v1 = vals[m][1], v2 = vals[m][2];
      const float mx = fmaxf(fmaxf(v0, v1), v2);
      const float mn = fminf(fminf(v0, v1), v2);
      const float av = (v0 + v1 + v2) * (1.f / 3.f);
      constexpr int ZBL[5] = {0, 54, 108, 162, 216};   // global ZB - 432
      const int cb = ZBL[m] + r * 3;
      acc(cb + 0, v0);
      acc(cb + 1, v1);
      acc(cb + 2, v2);
      acc(ZBL[m] + 27 + r, neg ? mn : mx);
      acc(ZBL[m] + 36 + r, av);
      acc(ZBL[m] + 45 + r, neg ? mx : mn);
    }
  }
  __syncthreads();   // rowstats visible; chunk-1 reads done

  // ---- chunk 2: cov block, global cols 0..215 -> local 0..215 ----
  load_chunk(0, 216);
  __syncthreads();
  for (int p = q; p < 36; p += 4) {
    const int X = d_PX[p], Y = d_PY[p];
    float zx[30], zy[30];
#pragma unroll
    for (int t = 0; t < 15; ++t) {
      float2 a = *reinterpret_cast<const float2*>(dptr + X * 30 + 2 * t);
      float2 c = *reinterpret_cast<const float2*>(dptr + Y * 30 + 2 * t);
      zx[2*t] = a.x; zx[2*t+1] = a.y;
      zy[2*t] = c.x; zy[2*t+1] = c.y;
    }
    float cv[3];
#pragma unroll
    for (int s = 0; s < 3; ++s) {
      float sxy = 0.f;
#pragma unroll
      for (int k = 0; k < 10; ++k) sxy = fmaf(zx[s*10 + k], zy[s*10 + k], sxy);
      float cov = (sxy - re[X*3 + s] * re[Y*3 + s] * 0.1f) * (1.f / 9.f);
      cv[s] = cov;
      acc(p*3 + s, cov);
    }
    const float mx = fmaxf(fmaxf(cv[0], cv[1]), cv[2]);
    const float mn = fminf(fminf(cv[0], cv[1]), cv[2]);
    const float av = (cv[0] + cv[1] + cv[2]) * (1.f / 3.f);
    acc(108 + p, neg ? mn : mx);
    acc(144 + p, av);
    acc(180 + p, neg ? mx : mn);
  }
  __syncthreads();

  // ---- chunk 3: corr block, global cols 216..431 -> local 0..215 ----
  load_chunk(216, 216);
  __syncthreads();
  for (int p = q; p < 36; p += 4) {
    const int X = d_PX[p], Y = d_PY[p];
    float zx[30], zy[30];
#pragma unroll
    for (int t = 0; t < 15; ++t) {
      float2 a = *reinterpret_cast<const float2*>(dptr + X * 30 + 2 * t);
      float2 c = *reinterpret_cast<const float2*>(dptr + Y * 30 + 2 * t);
      zx[2*t] = a.x; zx[2*t+1] = a.y;
      zy[2*t] = c.x; zy[2*t+1] = c.y;
    }
    float cr[3];
#pragma unroll
    for (int s = 0; s < 3; ++s) {
      float sxy = 0.f;
#pragma unroll
      for (int k = 0; k < 10; ++k) sxy = fmaf(zx[s*10 + k], zy[s*10 + k], sxy);
      float cov = (sxy - re[X*3 + s] * re[Y*3 + s] * 0.1f) * (1.f / 9.f);
      cr[s] = cov * re[27 + X*3 + s] * re[27 + Y*3 + s];
      acc(p*3 + s, cr[s]);
    }
    const float mx = fmaxf(fmaxf(cr[0], cr[1]), cr[2]);
    const float mn = fminf(fminf(cr[0], cr[1]), cr[2]);
    const float av = (cr[0] + cr[1] + cr[2]) * (1.f / 3.f);
    acc(108 + p, neg ? mn : mx);
    acc(144 + p, av);
    acc(180 + p, neg ? mx : mn);
  }

  // ---- combine 4 lanes' partial h (quad-aligned), epilogue (Round-0 verbatim) ----
#pragma unroll
  for (int t = 0; t < 8; ++t) {
    h[t].x += __shfl_xor(h[t].x, 1); h[t].y += __shfl_xor(h[t].y, 1);
    h[t].z += __shfl_xor(h[t].z, 1); h[t].w += __shfl_xor(h[t].w, 1);
    h[t].x += __shfl_xor(h[t].x, 2); h[t].y += __shfl_xor(h[t].y, 2);
    h[t].z += __shfl_xor(h[t].z, 2); h[t].w += __shfl_xor(h[t].w, 2);
  }
  if (q == 0 && b < NB) {
    float o = b2[0];
#pragma unroll
    for (int j = 0; j < 30; ++j) {
      const int t = j >> 2, c = j & 3;
      float hv = (c == 0) ? h[t].x : (c == 1) ? h[t].y : (c == 2) ? h[t].z : h[t].w;
      hv += b1f[j];
      o = fmaf(W2[j], fmaxf(hv, 0.f), o);
    }
    out[b] = o;
  }
}

// ---------------- STATS: Round-0 alpha_main<true> verbatim (PASSED on HW) ----------------
__launch_bounds__(TPB, 3)
__global__ void alpha_stats(const float* __restrict__ data, double* __restrict__ stats)
{
  __shared__ float lds[EPB * LSTR];
  __shared__ double rb[4][56];
  const int tid = threadIdx.x;
  const int e = tid >> 2, q = tid & 3;
  const int b = blockIdx.x * EPB + e;
  const float act = (b < NB) ? 1.f : 0.f;
  const int bb = (b < NB) ? b : (NB - 1);
  const float* __restrict__ dptr = data + (size_t)bb * 270;
  float* __restrict__ L = &lds[e * LSTR];

  float zS1[5], zS2[5], zMx[5], zMx2[5], zAv[5], zAv2[5], zMn[5], zMn2[5];
  float cS[16];
#pragma unroll
  for (int m = 0; m < 5; ++m) {
    zS1[m]=0.f; zS2[m]=0.f; zMx[m]=0.f; zMx2[m]=0.f;
    zAv[m]=0.f; zAv2[m]=0.f; zMn[m]=0.f; zMn2[m]=0.f;
  }
#pragma unroll
  for (int k = 0; k < 16; ++k) cS[k] = 0.f;

  // phase 1: rows owned by lane q
  for (int r = q; r < 9; r += 4) {
    float z[30];
#pragma unroll
    for (int t = 0; t < 15; ++t) {
      float2 v = *reinterpret_cast<const float2*>(dptr + r * 30 + 2 * t);
      z[2*t] = v.x; z[2*t+1] = v.y;
    }
    float vals[5][3];
#pragma unroll
    for (int s = 0; s < 3; ++s) {
      float sum = 0.f, ssq = 0.f, dec = 0.f;
#pragma unroll
      for (int k = 0; k < 10; ++k) {
        float zz = z[s*10 + k];
        sum += zz;
        ssq = fmaf(zz, zz, ssq);
        dec = fmaf(zz, (float)((double)(k + 1) / 55.0), dec);
      }
      float mZ = sum * 0.1f;
      float var1 = (ssq - sum * sum * 0.1f) * (1.f / 9.f);
      var1 = fmaxf(var1, 1e-30f);
      float sZ  = sqrtf(var1);
      float zsc = mZ / sZ;
      float rt  = z[s*10 + 9] / z[s*10] - 1.f;
      vals[0][s] = sZ; vals[1][s] = dec; vals[2][s] = zsc; vals[3][s] = rt; vals[4][s] = mZ;
      L[r*3 + s] = sum;
      L[27 + r*3 + s] = 1.f / sZ;
    }
#pragma unroll
    for (int m = 0; m < 5; ++m) {
      float v0 = vals[m][0], v1 = vals[m][1], v2 = vals[m][2];
      float mx = fmaxf(fmaxf(v0, v1), v2);
      float mn = fminf(fminf(v0, v1), v2);
      float av = (v0 + v1 + v2) * (1.f / 3.f);
      zS1[m]  += act * (v0 + v1 + v2);
      zS2[m]  += act * (v0*v0 + v1*v1 + v2*v2);
      zMx[m]  += act * mx;  zMx2[m] += act * mx * mx;
      zAv[m]  += act * av;  zAv2[m] += act * av * av;
      zMn[m]  += act * mn;  zMn2[m] += act * mn * mn;
    }
  }
  __syncthreads();

  // phase 2: pairs owned by lane q
  for (int p = q; p < 36; p += 4) {
    const int X = d_PX[p], Y = d_PY[p];
    float zx[30], zy[30];
#pragma unroll
    for (int t = 0; t < 15; ++t) {
      float2 a = *reinterpret_cast<const float2*>(dptr + X * 30 + 2 * t);
      float2 c = *reinterpret_cast<const float2*>(dptr + Y * 30 + 2 * t);
      zx[2*t] = a.x; zx[2*t+1] = a.y;
      zy[2*t] = c.x; zy[2*t+1] = c.y;
    }
    float cv[3], cr[3];
#pragma unroll
    for (int s = 0; s < 3; ++s) {
      float sxy = 0.f;
#pragma unroll
      for (int k = 0; k < 10; ++k) sxy = fmaf(zx[s*10 + k], zy[s*10 + k], sxy);
      float sX = L[X*3 + s], sY = L[Y*3 + s];
      float cov = (sxy - sX * sY * 0.1f) * (1.f / 9.f);
      cv[s] = cov;
      cr[s] = cov * L[27 + X*3 + s] * L[27 + Y*3 + s];
    }
    {
      float v0 = cv[0], v1 = cv[1], v2 = cv[2];
      float mx = fmaxf(fmaxf(v0, v1), v2);
      float mn = fminf(fminf(v0, v1), v2);
      float av = (v0 + v1 + v2) * (1.f / 3.f);
      cS[0] += act * (v0 + v1 + v2);
      cS[1] += act * (v0*v0 + v1*v1 + v2*v2);
      cS[2] += act * mx; cS[3] += act * mx * mx;
      cS[4] += act * av; cS[5] += act * av * av;
      cS[6] += act * mn; cS[7] += act * mn * mn;
    }
    {
      float v0 = cr[0], v1 = cr[1], v2 = cr[2];
      float mx = fmaxf(fmaxf(v0, v1), v2);
      float mn = fminf(fminf(v0, v1), v2);
      float av = (v0 + v1 + v2) * (1.f / 3.f);
      cS[8]  += act * (v0 + v1 + v2);
      cS[9]  += act * (v0*v0 + v1*v1 + v2*v2);
      cS[10] += act * mx; cS[11] += act * mx * mx;
      cS[12] += act * av; cS[13] += act * av * av;
      cS[14] += act * mn; cS[15] += act * mn * mn;
    }
  }

  const int wv = tid >> 6, ln = tid & 63;
  auto red1 = [&](float v, int idx) {
    double d = (double)v;
#pragma unroll
    for (int o = 32; o > 0; o >>= 1) d += __shfl_xor(d, o);
    if (ln == 0) rb[wv][idx] = d;
  };
#pragma unroll
  for (int m = 0; m < 5; ++m) {
    red1(zS1[m], (2+m)*8 + 0); red1(zS2[m],  (2+m)*8 + 1);
    red1(zMx[m], (2+m)*8 + 2); red1(zMx2[m], (2+m)*8 + 3);
    red1(zAv[m], (2+m)*8 + 4); red1(zAv2[m], (2+m)*8 + 5);
    red1(zMn[m], (2+m)*8 + 6); red1(zMn2[m], (2+m)*8 + 7);
  }
#pragma unroll
  for (int k = 0; k < 8; ++k) { red1(cS[k], k); red1(cS[8+k], 8 + k); }
  __syncthreads();
  if (tid < 56) {
    double t = rb[0][tid] + rb[1][tid] + rb[2][tid] + rb[3][tid];
    atomicAdd(&stats[tid], t);
  }
}

// ---------------- fold: Round-0 VERBATIM (stride 32, PASSED on HW) ----------------
__launch_bounds__(256)
__global__ void alpha_fold(const double* __restrict__ stats,
                           const float* __restrict__ gp, const float* __restrict__ bp,
                           const float* __restrict__ W1, const float* __restrict__ b1,
                           float* __restrict__ wt, float* __restrict__ b1f)
{
  __shared__ float A_[28], C_[28], sb[30];
  const int tid = threadIdx.x;
  const float gam = gp[0], bet = bp[0];
  const bool neg = (gam < 0.f);
  if (tid < 28) {
    const int m = tid >> 2, kd = tid & 3;
    const int Rm = (m < 2) ? 36 : 9;
    const double Nc = (double)NB * Rm * 3.0;
    const double Np = (double)NB * Rm;
    double mu0 = stats[m*8 + 0] / Nc;
    double v0  = stats[m*8 + 1] / Nc - mu0 * mu0; if (v0 < 0.0) v0 = 0.0;
    double a0 = (double)gam / sqrt(v0 + 1e-5);
    double c0 = (double)bet - a0 * mu0;
    double Av, Cv;
    if (kd == 0) { Av = a0; Cv = c0; }
    else {
      int k0;
      if (kd == 2) k0 = 4;                 // avg
      else if (kd == 1) k0 = neg ? 6 : 2;  // max slot (swap when gamma<0)
      else k0 = neg ? 2 : 6;               // min slot
      double mp = stats[m*8 + k0] / Np;
      double vp = stats[m*8 + k0 + 1] / Np - mp * mp; if (vp < 0.0) vp = 0.0;
      double my = a0 * mp + c0;
      double vy = a0 * a0 * vp;
      double a1 = (double)gam / sqrt(vy + 1e-5);
      double c1 = (double)bet - a1 * my;
      Av = a1 * a0; Cv = a1 * c0 + c1;
    }
    A_[tid] = (float)Av; C_[tid] = (float)Cv;
  }
  if (tid < 30) sb[tid] = 0.f;
  __syncthreads();
  for (int i = tid; i < 702; i += 256) {
    int m, base;
    if (i < 216)      { m = 0; base = 0; }
    else if (i < 432) { m = 1; base = 216; }
    else { int t = (i - 432) / 54; m = 2 + t; base = 432 + t * 54; }
    const int off = i - base;
    const int Rm = (m < 2) ? 36 : 9;
    const int kd = (off < Rm*3) ? 0 : (off < Rm*4) ? 1 : (off < Rm*5) ? 2 : 3;
    const float Av = A_[m*4 + kd], Cv = C_[m*4 + kd];
    for (int j = 0; j < 30; ++j) {
      float w = W1[j * 702 + i];
      wt[i * 32 + j] = w * Av;
      atomicAdd(&sb[j], w * Cv);
    }
    wt[i * 32 + 30] = 0.f; wt[i * 32 + 31] = 0.f;
  }
  __syncthreads();
  if (tid < 30) b1f[tid] = b1[tid] + sb[tid];
}

extern "C" void kernel_launch(void* const* d_in, const int* in_sizes, int n_in,
                              void* d_out, int out_size, void* d_ws, size_t ws_size,
                              hipStream_t stream) {
  const float* data = (const float*)d_in[0];
  const float* gam  = (const float*)d_in[1];
  const float* bet  = (const float*)d_in[2];
  const float* W1   = (const float*)d_in[3];
  const float* b1   = (const float*)d_in[4];
  const float* W2   = (const float*)d_in[5];
  const float* b2   = (const float*)d_in[6];
  float* out = (float*)d_out;

  double* stats = (double*)d_ws;                    // 56 doubles
  float*  b1f   = (float*)((char*)d_ws + 512);      // 30 floats
  float*  wt    = (float*)((char*)d_ws + 1024);     // 702*32 floats (~88 KB, Round-0-proven size)

  hipMemsetAsync(stats, 0, 56 * sizeof(double), stream);
  alpha_stats<<<GRID, TPB, 0, stream>>>(data, stats);
  alpha_fold <<<1,    256, 0, stream>>>(stats, gam, bet, W1, b1, wt, b1f);
  alpha_gemv <<<GRID, TPB, 0, stream>>>(data, gam, wt, b1f, W2, b2, out);
}